// Round 1
// baseline (1590.375 us; speedup 1.0000x reference)
//
#include <hip/hip_runtime.h>

#define V_DIM 128256
#define K_DIM 2048
#define M_DIM 2048
#define NVB (V_DIM / 128)  // 1002 vocab blocks of 128

using f32x4  = __attribute__((ext_vector_type(4))) float;
using bf16x8 = __attribute__((ext_vector_type(8))) short;

// round-to-nearest-even f32 -> bf16 (as ushort)
static __device__ __forceinline__ unsigned short f2b(float f) {
  unsigned int x = __float_as_uint(f);
  unsigned int r = (x + 0x7fffu + ((x >> 16) & 1u)) >> 16;
  return (unsigned short)r;
}

// ---------------- x f32 -> bf16 ----------------
__global__ __launch_bounds__(256) void cvt_x(const float* __restrict__ x,
                                             unsigned short* __restrict__ xb) {
  const size_t i = ((size_t)blockIdx.x * 256 + threadIdx.x) * 8;
  const float4 a = *(const float4*)&x[i];
  const float4 b = *(const float4*)&x[i + 4];
  union { unsigned short u[8]; uint4 v; } o;
  o.u[0] = f2b(a.x); o.u[1] = f2b(a.y); o.u[2] = f2b(a.z); o.u[3] = f2b(a.w);
  o.u[4] = f2b(b.x); o.u[5] = f2b(b.y); o.u[6] = f2b(b.z); o.u[7] = f2b(b.w);
  *(uint4*)&xb[i] = o.v;
}

// ---------------- W chunk transpose: [K][V] f32 -> [cc][K] bf16 ----------------
__global__ __launch_bounds__(256) void transpose_w(const float* __restrict__ wgt,
                                                   unsigned short* __restrict__ wtc,
                                                   int c0) {
  __shared__ unsigned short tile[64][65];  // +1 pad breaks bank conflicts
  const int t  = threadIdx.x;
  const int cb = blockIdx.x * 64;   // chunk-local col base
  const int kb = blockIdx.y * 64;
  const int tc4 = (t & 15) * 4;
  const int tk  = t >> 4;
#pragma unroll
  for (int p = 0; p < 4; ++p) {
    const int k = kb + tk + p * 16;
    const float4 v = *(const float4*)&wgt[(size_t)k * V_DIM + (c0 + cb + tc4)];
    tile[tc4 + 0][tk + p * 16] = f2b(v.x);
    tile[tc4 + 1][tk + p * 16] = f2b(v.y);
    tile[tc4 + 2][tk + p * 16] = f2b(v.z);
    tile[tc4 + 3][tk + p * 16] = f2b(v.w);
  }
  __syncthreads();
  const int wk4 = (t & 15) * 4;
  const int wc  = t >> 4;
#pragma unroll
  for (int p = 0; p < 4; ++p) {
    const int c = wc + p * 16;  // local col within tile
    ushort4 o;
    o.x = tile[c][wk4 + 0];
    o.y = tile[c][wk4 + 1];
    o.z = tile[c][wk4 + 2];
    o.w = tile[c][wk4 + 3];
    *(ushort4*)&wtc[(size_t)(cb + c) * K_DIM + (kb + wk4)] = o;
  }
}

// ---------------- fused GEMM + partial sum-of-exp ----------------
// xb: [2048][2048] bf16, wt: [cc][2048] bf16 (chunk-local rows = vocab cols)
// partial[row][vb] = sum_{v in block vb} exp(logit[row][v])
__global__ __launch_bounds__(256) void gemm_lse(const unsigned short* __restrict__ xb,
                                                const unsigned short* __restrict__ wt,
                                                float* __restrict__ partial,
                                                int vb0) {
  __shared__ unsigned short Al[128 * 64];
  __shared__ unsigned short Bl[128 * 64];
  __shared__ float red[2][128];

  const int tid = threadIdx.x;
  const int w = tid >> 6;
  const int l = tid & 63;
  const int m0 = blockIdx.y * 128;
  const int n0 = blockIdx.x * 128;  // chunk-local vocab base
  const int wm = w >> 1, wn = w & 1;

  // staging: wave w, issue i covers LDS rows (w*4+i)*8 .. +8, lane l -> row +l>>3, col-block l&7
  // T2 swizzle: LDS(row, c) holds G(row, c ^ ((row&7)<<3)); row&7 == l>>3 here
  const int srow = (w * 4) * 8 + (l >> 3);
  const int scol = (((l & 7) ^ (l >> 3)) * 8);

  f32x4 acc[4][4] = {};

  const unsigned short* gA = &xb[(size_t)(m0 + srow) * K_DIM + scol];
  const unsigned short* gB = &wt[(size_t)(n0 + srow) * K_DIM + scol];

  for (int kt = 0; kt < K_DIM / 64; ++kt) {
    __syncthreads();
#pragma unroll
    for (int i = 0; i < 4; ++i) {
      __builtin_amdgcn_global_load_lds(
          (const __attribute__((address_space(1))) void*)(gA + (size_t)i * 8 * K_DIM),
          (__attribute__((address_space(3))) void*)&Al[(w * 4 + i) * 512], 16, 0, 0);
    }
#pragma unroll
    for (int i = 0; i < 4; ++i) {
      __builtin_amdgcn_global_load_lds(
          (const __attribute__((address_space(1))) void*)(gB + (size_t)i * 8 * K_DIM),
          (__attribute__((address_space(3))) void*)&Bl[(w * 4 + i) * 512], 16, 0, 0);
    }
    gA += 64;
    gB += 64;
    __syncthreads();

#pragma unroll
    for (int s = 0; s < 2; ++s) {
      // fragment k-offset with read-side swizzle (row&7 == l&7 for frag rows)
      const int kx = (s * 32 + ((l >> 4) * 8)) ^ ((l & 7) << 3);
      bf16x8 af[4], bfr[4];
#pragma unroll
      for (int mi = 0; mi < 4; ++mi)
        af[mi] = *(const bf16x8*)&Al[(wm * 64 + mi * 16 + (l & 15)) * 64 + kx];
#pragma unroll
      for (int ni = 0; ni < 4; ++ni)
        bfr[ni] = *(const bf16x8*)&Bl[(wn * 64 + ni * 16 + (l & 15)) * 64 + kx];
#pragma unroll
      for (int mi = 0; mi < 4; ++mi)
#pragma unroll
        for (int ni = 0; ni < 4; ++ni)
          acc[mi][ni] = __builtin_amdgcn_mfma_f32_16x16x32_bf16(af[mi], bfr[ni],
                                                                acc[mi][ni], 0, 0, 0);
    }
  }

  // ---- epilogue: per-row sum of exp over this block's 128 cols ----
  // C/D layout: col = lane&15 (+ni*16+wn*64), row = (lane>>4)*4 + reg (+mi*16+wm*64)
  float rsum[4][4];
#pragma unroll
  for (int mi = 0; mi < 4; ++mi)
#pragma unroll
    for (int r = 0; r < 4; ++r) {
      float s = 0.f;
#pragma unroll
      for (int ni = 0; ni < 4; ++ni)
        s += exp2f(acc[mi][ni][r] * 1.4426950408889634f);
      rsum[mi][r] = s;
    }
#pragma unroll
  for (int off = 1; off <= 8; off <<= 1)
#pragma unroll
    for (int mi = 0; mi < 4; ++mi)
#pragma unroll
      for (int r = 0; r < 4; ++r)
        rsum[mi][r] += __shfl_xor(rsum[mi][r], off, 64);

  if ((l & 15) == 0) {
    const int g = l >> 4;
#pragma unroll
    for (int mi = 0; mi < 4; ++mi)
#pragma unroll
      for (int r = 0; r < 4; ++r)
        red[wn][wm * 64 + mi * 16 + g * 4 + r] = rsum[mi][r];
  }
  __syncthreads();
  if (tid < 128) {
    const float tot = red[0][tid] + red[1][tid];
    partial[(size_t)(m0 + tid) * NVB + (vb0 + blockIdx.x)] = tot;
  }
}

// ---------------- exact f32 target logit: t[row] = x[row,:] . W[:,label] ----------------
__global__ __launch_bounds__(256) void target_dot(const float* __restrict__ x,
                                                  const float* __restrict__ wgt,
                                                  const int* __restrict__ labels,
                                                  float* __restrict__ tgt) {
  const int row = blockIdx.x;
  int lab = labels[row];
  lab = lab < 0 ? 0 : (lab >= V_DIM ? V_DIM - 1 : lab);
  float s = 0.f;
  for (int k = threadIdx.x; k < K_DIM; k += 256)
    s += x[(size_t)row * K_DIM + k] * wgt[(size_t)k * V_DIM + lab];
#pragma unroll
  for (int off = 1; off < 64; off <<= 1) s += __shfl_xor(s, off, 64);
  __shared__ float w4[4];
  if ((threadIdx.x & 63) == 0) w4[threadIdx.x >> 6] = s;
  __syncthreads();
  if (threadIdx.x == 0) tgt[row] = (w4[0] + w4[1]) + (w4[2] + w4[3]);
}

// ---------------- final reduce: lse + loss ----------------
__global__ __launch_bounds__(256) void reduce_lse(const float* __restrict__ partial,
                                                  const float* __restrict__ tgt,
                                                  const int* __restrict__ labels,
                                                  float* __restrict__ out) {
  const int row = blockIdx.x;
  float s = 0.f;
  for (int vb = threadIdx.x; vb < NVB; vb += 256)
    s += partial[(size_t)row * NVB + vb];
#pragma unroll
  for (int off = 1; off < 64; off <<= 1) s += __shfl_xor(s, off, 64);
  __shared__ float w4[4];
  if ((threadIdx.x & 63) == 0) w4[threadIdx.x >> 6] = s;
  __syncthreads();
  if (threadIdx.x == 0) {
    const float tot = (w4[0] + w4[1]) + (w4[2] + w4[3]);
    const float lse = logf(tot);  // fixed shift 0: logits bounded ~|6|, safe in f32
    const float loss = (labels[row] != -100) ? (lse - tgt[row]) : 0.f;
    out[row] = loss;
    out[M_DIM + row] = lse;
  }
}

extern "C" void kernel_launch(void* const* d_in, const int* in_sizes, int n_in,
                              void* d_out, int out_size, void* d_ws, size_t ws_size,
                              hipStream_t stream) {
  const float* x = (const float*)d_in[0];
  const float* wgt = (const float*)d_in[1];
  const int* labels = (const int*)d_in[2];
  float* out = (float*)d_out;

  char* ws = (char*)d_ws;
  unsigned short* xb = (unsigned short*)ws;
  size_t off = (size_t)M_DIM * K_DIM * 2;  // 8 MB
  float* partial = (float*)(ws + off);
  off += (size_t)M_DIM * NVB * 4;          // 8.2 MB
  float* tgt = (float*)(ws + off);
  off += (size_t)M_DIM * 4;
  off = (off + 255) & ~(size_t)255;
  unsigned short* wtc = (unsigned short*)(ws + off);
  const size_t avail = ws_size > off ? ws_size - off : 0;
  int CC = 16384;  // chunk of vocab cols (multiple of 128)
  while (CC > 128 && (size_t)CC * K_DIM * 2 > avail) CC >>= 1;

  cvt_x<<<dim3(M_DIM * K_DIM / (256 * 8)), dim3(256), 0, stream>>>(x, xb);
  target_dot<<<dim3(M_DIM), dim3(256), 0, stream>>>(x, wgt, labels, tgt);
  for (int c0 = 0; c0 < V_DIM; c0 += CC) {
    int cc = V_DIM - c0;
    if (cc > CC) cc = CC;
    transpose_w<<<dim3(cc / 64, K_DIM / 64), dim3(256), 0, stream>>>(wgt, wtc, c0);
    gemm_lse<<<dim3(cc / 128, M_DIM / 128), dim3(256), 0, stream>>>(xb, wtc, partial,
                                                                    c0 / 128);
  }
  reduce_lse<<<dim3(M_DIM), dim3(256), 0, stream>>>(partial, tgt, labels, out);
}

// Round 3
// 1378.893 us; speedup vs baseline: 1.1534x; 1.1534x over previous
//
#include <hip/hip_runtime.h>

#define V_DIM 128256
#define K_DIM 2048
#define M_DIM 2048
#define NPB (V_DIM / 256)  // 501 vocab blocks of 256

using f32x4  = __attribute__((ext_vector_type(4))) float;
using bf16x8 = __attribute__((ext_vector_type(8))) short;

// round-to-nearest-even f32 -> bf16 (as ushort)
static __device__ __forceinline__ unsigned short f2b(float f) {
  unsigned int x = __float_as_uint(f);
  unsigned int r = (x + 0x7fffu + ((x >> 16) & 1u)) >> 16;
  return (unsigned short)r;
}

// ---------------- x f32 -> bf16 ----------------
__global__ __launch_bounds__(256) void cvt_x(const float* __restrict__ x,
                                             unsigned short* __restrict__ xb) {
  const size_t i = ((size_t)blockIdx.x * 256 + threadIdx.x) * 8;
  const float4 a = *(const float4*)&x[i];
  const float4 b = *(const float4*)&x[i + 4];
  union { unsigned short u[8]; uint4 v; } o;
  o.u[0] = f2b(a.x); o.u[1] = f2b(a.y); o.u[2] = f2b(a.z); o.u[3] = f2b(a.w);
  o.u[4] = f2b(b.x); o.u[5] = f2b(b.y); o.u[6] = f2b(b.z); o.u[7] = f2b(b.w);
  *(uint4*)&xb[i] = o.v;
}

// ---------------- W chunk transpose: [K][V] f32 -> [cc][K] bf16 ----------------
__global__ __launch_bounds__(256) void transpose_w(const float* __restrict__ wgt,
                                                   unsigned short* __restrict__ wtc,
                                                   int c0) {
  __shared__ unsigned short tile[64][65];
  const int t  = threadIdx.x;
  const int cb = blockIdx.x * 64;
  const int kb = blockIdx.y * 64;
  const int tc4 = (t & 15) * 4;
  const int tk  = t >> 4;
#pragma unroll
  for (int p = 0; p < 4; ++p) {
    const int k = kb + tk + p * 16;
    const float4 v = *(const float4*)&wgt[(size_t)k * V_DIM + (c0 + cb + tc4)];
    tile[tc4 + 0][tk + p * 16] = f2b(v.x);
    tile[tc4 + 1][tk + p * 16] = f2b(v.y);
    tile[tc4 + 2][tk + p * 16] = f2b(v.z);
    tile[tc4 + 3][tk + p * 16] = f2b(v.w);
  }
  __syncthreads();
  const int wk4 = (t & 15) * 4;
  const int wc  = t >> 4;
#pragma unroll
  for (int p = 0; p < 4; ++p) {
    const int c = wc + p * 16;
    ushort4 o;
    o.x = tile[c][wk4 + 0];
    o.y = tile[c][wk4 + 1];
    o.z = tile[c][wk4 + 2];
    o.w = tile[c][wk4 + 3];
    *(ushort4*)&wtc[(size_t)(cb + c) * K_DIM + (kb + wk4)] = o;
  }
}

// ---------------- 256x256 8-phase GEMM + partial sum-of-exp ----------------
// xb: [2048][2048] bf16; wt: [cc][2048] bf16 (rows = vocab cols).
// partial[row][vb] = sum over 256-col block of exp(logit).
//
// Schedule (race-free by construction): 4 phases per K-tile (BK=64).
// Phase q consumes A-quarter q (frags mi=2q,2q+1); B is fully reg-loaded at
// phase 0. Prefetch (2 global_load_lds/thread/phase) targets only regions
// whose consumption ended before the issuing phase began:
//   ph0: A(t+1)Q3, B(t+1)I3 -> buf^1 (dead since (t-1) finished)
//   ph1: A(t+2)Q0, B(t+2)I0 -> buf   (A Q0 + all B of tile t consumed in ph0)
//   ph2: A(t+2)Q1, B(t+2)I1
//   ph3: A(t+2)Q2, B(t+2)I2 ; vmcnt(6) retires everything tile t+1 needs.
#define MF(a, b, c) __builtin_amdgcn_mfma_f32_16x16x32_bf16(a, b, c, 0, 0, 0)

#define STAGE_A(T, q, d) do {                                                   \
    const int rb_ = 32 * (q) + (w & 3) * 8 + (w >> 2) * 128;                    \
    __builtin_amdgcn_global_load_lds(                                           \
        (const __attribute__((address_space(1))) void*)                         \
            &xb[(size_t)(m0 + rb_ + lr) * K_DIM + (T) * 64 + sw8],              \
        (__attribute__((address_space(3))) void*)&Al[d][rb_ * 64], 16, 0, 0);   \
  } while (0)

#define STAGE_B(T, i, d) do {                                                   \
    const int rb_ = (i) * 64 + w * 8;                                           \
    __builtin_amdgcn_global_load_lds(                                           \
        (const __attribute__((address_space(1))) void*)                         \
            &wt[(size_t)(n0 + rb_ + lr) * K_DIM + (T) * 64 + sw8],              \
        (__attribute__((address_space(3))) void*)&Bl[d][rb_ * 64], 16, 0, 0);   \
  } while (0)

#define RD_A(c, mi, s) (*(const bf16x8*)&Al[c][(wm * 128 + (mi) * 16 + (l & 15)) * 64 + \
                                               ((((s) * 4 + (l >> 4)) ^ (l & 7)) * 8)])
#define RD_B(c, ni, s) (*(const bf16x8*)&Bl[c][(wn * 64 + (ni) * 16 + (l & 15)) * 64 + \
                                               ((((s) * 4 + (l >> 4)) ^ (l & 7)) * 8)])

#define MFMA8(mi, aa0, aa1)                                        \
  acc[mi][0] = MF(aa0, bfr[0][0], acc[mi][0]);                     \
  acc[mi][0] = MF(aa1, bfr[0][1], acc[mi][0]);                     \
  acc[mi][1] = MF(aa0, bfr[1][0], acc[mi][1]);                     \
  acc[mi][1] = MF(aa1, bfr[1][1], acc[mi][1]);                     \
  acc[mi][2] = MF(aa0, bfr[2][0], acc[mi][2]);                     \
  acc[mi][2] = MF(aa1, bfr[2][1], acc[mi][2]);                     \
  acc[mi][3] = MF(aa0, bfr[3][0], acc[mi][3]);                     \
  acc[mi][3] = MF(aa1, bfr[3][1], acc[mi][3]);

#define PHASE(q) {                                                              \
    bf16x8 a0 = RD_A(cb, 2 * (q), 0), a1 = RD_A(cb, 2 * (q), 1);                \
    bf16x8 a2 = RD_A(cb, 2 * (q) + 1, 0), a3 = RD_A(cb, 2 * (q) + 1, 1);        \
    if (t + 2 < K_DIM / 64) { STAGE_A(t + 2, (q) - 1, cb); STAGE_B(t + 2, (q) - 1, cb); } \
    if ((q) == 3) {                                                             \
      if (t < K_DIM / 64 - 2) asm volatile("s_waitcnt vmcnt(6)" ::: "memory");  \
      else                    asm volatile("s_waitcnt vmcnt(0)" ::: "memory");  \
    }                                                                           \
    __builtin_amdgcn_s_barrier();                                               \
    asm volatile("s_waitcnt lgkmcnt(0)" ::: "memory");                          \
    __builtin_amdgcn_s_setprio(1);                                              \
    MFMA8(2 * (q), a0, a1);                                                     \
    MFMA8(2 * (q) + 1, a2, a3);                                                 \
    __builtin_amdgcn_s_setprio(0);                                              \
    __builtin_amdgcn_s_barrier();                                               \
  }

__global__ __launch_bounds__(512, 2) void gemm_lse(const unsigned short* __restrict__ xb,
                                                   const unsigned short* __restrict__ wt,
                                                   float* __restrict__ partial,
                                                   int vb0, int nbx) {
  __shared__ unsigned short Al[2][256 * 64];
  __shared__ unsigned short Bl[2][256 * 64];

  const int tid = threadIdx.x;
  const int w = tid >> 6, l = tid & 63;
  const int wm = w >> 2, wn = w & 3;

  // bijective XCD swizzle (nwg = nbx*8, always %8==0); 8 consecutive share B-panel
  const int nwg = nbx * 8;
  const int swz = (blockIdx.x & 7) * (nwg >> 3) + (blockIdx.x >> 3);
  const int m0 = (swz & 7) * 256;
  const int n0 = (swz >> 3) * 256;

  const int lr = l >> 3;
  const int sw8 = ((l & 7) ^ lr) * 8;

  f32x4 acc[8][4] = {};
  bf16x8 bfr[4][2];

  // prologue: tile0 fully + tile1 quarters/issues 0-2
  STAGE_A(0, 0, 0); STAGE_A(0, 1, 0); STAGE_A(0, 2, 0); STAGE_A(0, 3, 0);
  STAGE_B(0, 0, 0); STAGE_B(0, 1, 0); STAGE_B(0, 2, 0); STAGE_B(0, 3, 0);
  STAGE_A(1, 0, 1); STAGE_B(1, 0, 1);
  STAGE_A(1, 1, 1); STAGE_B(1, 1, 1);
  STAGE_A(1, 2, 1); STAGE_B(1, 2, 1);
  asm volatile("s_waitcnt vmcnt(6)" ::: "memory");
  __builtin_amdgcn_s_barrier();

#pragma unroll 1
  for (int t = 0; t < K_DIM / 64; ++t) {
    const int cb = t & 1;
    // ---- phase 0: load all B + A quarter 0; prefetch (t+1) Q3/I3 ----
    {
      bfr[0][0] = RD_B(cb, 0, 0); bfr[0][1] = RD_B(cb, 0, 1);
      bfr[1][0] = RD_B(cb, 1, 0); bfr[1][1] = RD_B(cb, 1, 1);
      bfr[2][0] = RD_B(cb, 2, 0); bfr[2][1] = RD_B(cb, 2, 1);
      bfr[3][0] = RD_B(cb, 3, 0); bfr[3][1] = RD_B(cb, 3, 1);
      bf16x8 a0 = RD_A(cb, 0, 0), a1 = RD_A(cb, 0, 1);
      bf16x8 a2 = RD_A(cb, 1, 0), a3 = RD_A(cb, 1, 1);
      if (t + 1 < K_DIM / 64) { STAGE_A(t + 1, 3, cb ^ 1); STAGE_B(t + 1, 3, cb ^ 1); }
      __builtin_amdgcn_s_barrier();
      asm volatile("s_waitcnt lgkmcnt(0)" ::: "memory");
      __builtin_amdgcn_s_setprio(1);
      MFMA8(0, a0, a1);
      MFMA8(1, a2, a3);
      __builtin_amdgcn_s_setprio(0);
      __builtin_amdgcn_s_barrier();
    }
    PHASE(1)
    PHASE(2)
    PHASE(3)
  }

  // ---- epilogue: per-row sum of exp over this block's 256 cols ----
  // C layout: row = wm*128 + mi*16 + (l>>4)*4 + r ; col = wn*64 + ni*16 + (l&15)
  float rs[8][4];
#pragma unroll
  for (int mi = 0; mi < 8; ++mi)
#pragma unroll
    for (int r = 0; r < 4; ++r) {
      float s = 0.f;
#pragma unroll
      for (int ni = 0; ni < 4; ++ni)
        s += exp2f(acc[mi][ni][r] * 1.4426950408889634f);
#pragma unroll
      for (int off = 1; off <= 8; off <<= 1) s += __shfl_xor(s, off, 64);
      rs[mi][r] = s;
    }
  __syncthreads();
  float* red = (float*)&Al[0][0];  // [4 wn][256 rows]
  if ((l & 15) == 0) {
#pragma unroll
    for (int mi = 0; mi < 8; ++mi)
#pragma unroll
      for (int r = 0; r < 4; ++r)
        red[wn * 256 + wm * 128 + mi * 16 + (l >> 4) * 4 + r] = rs[mi][r];
  }
  __syncthreads();
  if (tid < 256) {
    const float tot = (red[tid] + red[256 + tid]) + (red[512 + tid] + red[768 + tid]);
    partial[(size_t)(m0 + tid) * NPB + (vb0 + (swz >> 3))] = tot;
  }
}

// ---------------- exact f32 target logit ----------------
__global__ __launch_bounds__(256) void target_dot(const float* __restrict__ x,
                                                  const float* __restrict__ wgt,
                                                  const int* __restrict__ labels,
                                                  float* __restrict__ tgt) {
  const int row = blockIdx.x;
  int lab = labels[row];
  lab = lab < 0 ? 0 : (lab >= V_DIM ? V_DIM - 1 : lab);
  float s = 0.f;
  for (int k = threadIdx.x; k < K_DIM; k += 256)
    s += x[(size_t)row * K_DIM + k] * wgt[(size_t)k * V_DIM + lab];
#pragma unroll
  for (int off = 1; off < 64; off <<= 1) s += __shfl_xor(s, off, 64);
  __shared__ float w4[4];
  if ((threadIdx.x & 63) == 0) w4[threadIdx.x >> 6] = s;
  __syncthreads();
  if (threadIdx.x == 0) tgt[row] = (w4[0] + w4[1]) + (w4[2] + w4[3]);
}

// ---------------- final reduce ----------------
__global__ __launch_bounds__(256) void reduce_lse(const float* __restrict__ partial,
                                                  const float* __restrict__ tgt,
                                                  const int* __restrict__ labels,
                                                  float* __restrict__ out) {
  const int row = blockIdx.x;
  float s = 0.f;
  for (int vb = threadIdx.x; vb < NPB; vb += 256)
    s += partial[(size_t)row * NPB + vb];
#pragma unroll
  for (int off = 1; off < 64; off <<= 1) s += __shfl_xor(s, off, 64);
  __shared__ float w4[4];
  if ((threadIdx.x & 63) == 0) w4[threadIdx.x >> 6] = s;
  __syncthreads();
  if (threadIdx.x == 0) {
    const float tot = (w4[0] + w4[1]) + (w4[2] + w4[3]);
    const float lse = logf(tot);
    const float loss = (labels[row] != -100) ? (lse - tgt[row]) : 0.f;
    out[row] = loss;
    out[M_DIM + row] = lse;
  }
}

extern "C" void kernel_launch(void* const* d_in, const int* in_sizes, int n_in,
                              void* d_out, int out_size, void* d_ws, size_t ws_size,
                              hipStream_t stream) {
  const float* x = (const float*)d_in[0];
  const float* wgt = (const float*)d_in[1];
  const int* labels = (const int*)d_in[2];
  float* out = (float*)d_out;

  char* ws = (char*)d_ws;
  unsigned short* xb = (unsigned short*)ws;
  size_t off = (size_t)M_DIM * K_DIM * 2;
  float* partial = (float*)(ws + off);
  off += (size_t)M_DIM * NPB * 4;
  float* tgt = (float*)(ws + off);
  off += (size_t)M_DIM * 4;
  off = (off + 255) & ~(size_t)255;
  unsigned short* wtc = (unsigned short*)(ws + off);
  const size_t avail = ws_size > off ? ws_size - off : 0;
  int CC = 16384;
  while (CC > 256 && (size_t)CC * K_DIM * 2 > avail) CC >>= 1;

  cvt_x<<<dim3(M_DIM * K_DIM / (256 * 8)), dim3(256), 0, stream>>>(x, xb);
  target_dot<<<dim3(M_DIM), dim3(256), 0, stream>>>(x, wgt, labels, tgt);
  for (int c0 = 0; c0 < V_DIM; c0 += CC) {
    int cc = V_DIM - c0;
    if (cc > CC) cc = CC;
    transpose_w<<<dim3(cc / 64, K_DIM / 64), dim3(256), 0, stream>>>(wgt, wtc, c0);
    const int nbx = cc / 256;
    gemm_lse<<<dim3(nbx * 8), dim3(512), 0, stream>>>(xb, wtc, partial, c0 / 256, nbx);
  }
  reduce_lse<<<dim3(M_DIM), dim3(256), 0, stream>>>(partial, tgt, labels, out);
}